// Round 1
// baseline (495.242 us; speedup 1.0000x reference)
//
#include <hip/hip_runtime.h>

#define D_MODEL 1024
#define NB 8
#define SEQ 8192
#define CHUNKS 128                 // S-chunks per batch -> 8*128 = 1024 blocks (4/CU)
#define ROWS (SEQ / CHUNKS)        // 64 rows per chunk
#define RPI 8                      // rows processed per iteration
#define THREADS 256
#define NEG_BIG (-1e30f)

// d_ws layout:
//   [0..255]                bytes: int flag at offset 0 (mask element width detect)
//   float W[]:  W[0 .. 1024)            = m per (b,chunk)
//               W[1024 .. 2048)         = l per (b,chunk)
//               W[2048 .. 2048+1024*1024) = acc[b*CHUNKS+c][1024]
// total ~4.2 MB

__global__ void detect_fmt(const unsigned char* __restrict__ m, int* __restrict__ flag) {
    // If mask elements are 1 byte (bool), bytes at offsets %4 != 0 hold real ~Bernoulli(0.5)
    // values -> some nonzero. If elements are 4 bytes (int32 0/1 or float 0.0/1.0), those
    // byte positions are 0 (within the first NB*SEQ bytes, which exist in both layouts).
    int found = 0;
    for (int i = threadIdx.x; i < NB * SEQ; i += blockDim.x) {
        if ((i & 3) && m[i]) found = 1;
    }
    if (found) atomicOr(flag, 1);
}

__global__ __launch_bounds__(THREADS, 4)
void attn_partial(const float* __restrict__ x, const void* __restrict__ maskp,
                  const float* __restrict__ q, float* __restrict__ W,
                  const int* __restrict__ flag)
{
    const int bid = blockIdx.x;
    const int b   = bid >> 7;            // CHUNKS = 128
    const int c   = bid & (CHUNKS - 1);
    const int tid = threadIdx.x;
    const int s0  = c * ROWS;

    const float4 q4 = reinterpret_cast<const float4*>(q)[tid];   // tid in [0,256): covers 1024
    const bool u8fmt = (*flag != 0);
    const unsigned char* m8  = (const unsigned char*)maskp;
    const int*           m32 = (const int*)maskp;

    const float4* xb = reinterpret_cast<const float4*>(x) + ((size_t)b * SEQ + s0) * (D_MODEL / 4);

    __shared__ float red[4][RPI];

    float4 acc = make_float4(0.f, 0.f, 0.f, 0.f);
    float m_run = NEG_BIG;
    float l_run = 0.f;

    const int lane = tid & 63;
    const int wv   = tid >> 6;

    for (int r0 = 0; r0 < ROWS; r0 += RPI) {
        float4 xv[RPI];
        float  dt[RPI];
        #pragma unroll
        for (int j = 0; j < RPI; ++j)
            xv[j] = xb[(size_t)(r0 + j) * (D_MODEL / 4) + tid];

        #pragma unroll
        for (int j = 0; j < RPI; ++j) {
            float v = xv[j].x * q4.x;
            v = fmaf(xv[j].y, q4.y, v);
            v = fmaf(xv[j].z, q4.z, v);
            v = fmaf(xv[j].w, q4.w, v);
            #pragma unroll
            for (int off = 32; off > 0; off >>= 1)
                v += __shfl_xor(v, off, 64);
            dt[j] = v;                    // every lane now holds the wave sum
        }
        if (lane == 0) {
            #pragma unroll
            for (int j = 0; j < RPI; ++j) red[wv][j] = dt[j];
        }
        __syncthreads();

        float sc[RPI];
        #pragma unroll
        for (int j = 0; j < RPI; ++j) {
            float d = red[0][j] + red[1][j] + red[2][j] + red[3][j];
            int s = s0 + r0 + j;
            int mv = u8fmt ? (int)m8[(size_t)b * SEQ + s] : m32[(size_t)b * SEQ + s];
            sc[j] = mv ? NEG_BIG : d * 0.03125f;   // 1/sqrt(1024) = 1/32
        }
        __syncthreads();   // red[] reused next iteration

        float mb = sc[0];
        #pragma unroll
        for (int j = 1; j < RPI; ++j) mb = fmaxf(mb, sc[j]);
        float m_new = fmaxf(m_run, mb);
        float resc = __expf(m_run - m_new);   // 1 when both NEG_BIG; 0 when first real row
        acc.x *= resc; acc.y *= resc; acc.z *= resc; acc.w *= resc;
        l_run *= resc;
        #pragma unroll
        for (int j = 0; j < RPI; ++j) {
            float w = __expf(sc[j] - m_new);
            l_run += w;
            acc.x = fmaf(w, xv[j].x, acc.x);
            acc.y = fmaf(w, xv[j].y, acc.y);
            acc.z = fmaf(w, xv[j].z, acc.z);
            acc.w = fmaf(w, xv[j].w, acc.w);
        }
        m_run = m_new;
    }

    float* mArr = W;
    float* lArr = W + NB * CHUNKS;
    float* accArr = W + 2 * NB * CHUNKS + (size_t)bid * D_MODEL;
    reinterpret_cast<float4*>(accArr)[tid] = acc;
    if (tid == 0) { mArr[bid] = m_run; lArr[bid] = l_run; }
}

__global__ __launch_bounds__(THREADS)
void attn_combine(const float* __restrict__ W, float* __restrict__ out)
{
    const int b   = blockIdx.x;
    const int tid = threadIdx.x;
    const float* mArr = W + b * CHUNKS;
    const float* lArr = W + NB * CHUNKS + b * CHUNKS;
    const float* accBase = W + 2 * NB * CHUNKS + (size_t)b * CHUNKS * D_MODEL;

    float M = NEG_BIG;
    for (int k = 0; k < CHUNKS; ++k) M = fmaxf(M, mArr[k]);

    float L = 0.f;
    float4 o = make_float4(0.f, 0.f, 0.f, 0.f);
    #pragma unroll 4
    for (int k = 0; k < CHUNKS; ++k) {
        float f = __expf(mArr[k] - M);       // 0 for fully-masked chunks -> kills their junk
        L = fmaf(lArr[k], f, L);
        float4 a = reinterpret_cast<const float4*>(accBase + (size_t)k * D_MODEL)[tid];
        o.x = fmaf(f, a.x, o.x);
        o.y = fmaf(f, a.y, o.y);
        o.z = fmaf(f, a.z, o.z);
        o.w = fmaf(f, a.w, o.w);
    }
    float inv = 1.f / L;
    float4 r = make_float4(o.x * inv, o.y * inv, o.z * inv, o.w * inv);
    reinterpret_cast<float4*>(out)[b * (D_MODEL / 4) + tid] = r;
}

extern "C" void kernel_launch(void* const* d_in, const int* in_sizes, int n_in,
                              void* d_out, int out_size, void* d_ws, size_t ws_size,
                              hipStream_t stream) {
    const float* x    = (const float*)d_in[0];
    const void*  mask = d_in[1];
    const float* q    = (const float*)d_in[2];
    float* out  = (float*)d_out;
    int*   flag = (int*)d_ws;
    float* W    = (float*)((char*)d_ws + 256);

    hipMemsetAsync(d_ws, 0, 256, stream);   // zero the detect flag (ws is poisoned 0xAA)
    detect_fmt<<<1, THREADS, 0, stream>>>((const unsigned char*)mask, flag);
    attn_partial<<<NB * CHUNKS, THREADS, 0, stream>>>(x, mask, q, W, flag);
    attn_combine<<<NB, THREADS, 0, stream>>>(W, out);
}

// Round 2
// 370.114 us; speedup vs baseline: 1.3381x; 1.3381x over previous
//
#include <hip/hip_runtime.h>

#define D_MODEL 1024
#define NB 8
#define SEQ 8192
#define CHUNKS_PER_B 128           // one chunk per block -> 1024 blocks, 4 blocks/CU
#define ROWS_PER_BLOCK 64
#define ROWS_PER_WAVE 16
#define THREADS 256
#define NEG_BIG (-1e30f)

// d_ws float layout: mArr[1024] | lArr[1024] | acc[1024][1024]   (~4.2 MB)

__global__ __launch_bounds__(THREADS, 4)
void attn_partial(const float* __restrict__ x, const void* __restrict__ maskp,
                  const float* __restrict__ q, float* __restrict__ W)
{
    const int bid  = blockIdx.x;
    const int b    = bid >> 7;             // CHUNKS_PER_B = 128
    const int c    = bid & 127;
    const int tid  = threadIdx.x;
    const int lane = tid & 63;
    const int wv   = tid >> 6;

    __shared__ int   s_fmt;
    __shared__ float sm_m[4], sm_l[4];
    __shared__ float sm_acc[4][D_MODEL];

    // ---- inline mask element-width detection ----
    // First 256 words (1 KB) are in-bounds under both layouts (u8 buffer is 64 KB).
    // u8-truth: words are 4 packed Bernoulli bytes -> some word > 1 w.p. 1 - 8^-256.
    // i32-truth (0/1 values): all words <= 1.
    if (tid == 0) s_fmt = 0;
    __syncthreads();
    if (((const unsigned int*)maskp)[tid] > 1u) s_fmt = 1;   // benign same-value race
    __syncthreads();
    const bool u8fmt = (s_fmt != 0);
    const unsigned char* m8  = (const unsigned char*)maskp;
    const int*           m32 = (const int*)maskp;

    // ---- per-wave streaming: wave owns 16 consecutive rows; lane owns 16 columns ----
    const int    row0  = c * ROWS_PER_BLOCK + wv * ROWS_PER_WAVE;   // within batch
    const size_t srow0 = (size_t)b * SEQ + row0;
    const float4* xw   = reinterpret_cast<const float4*>(x) + srow0 * (D_MODEL / 4);
    const float4* q4p  = reinterpret_cast<const float4*>(q);

    float4 q4[4], acc[4];
    #pragma unroll
    for (int k = 0; k < 4; ++k) {
        q4[k]  = q4p[k * 64 + lane];
        acc[k] = make_float4(0.f, 0.f, 0.f, 0.f);
    }
    float m_run = NEG_BIG, l_run = 0.f;

    for (int it = 0; it < ROWS_PER_WAVE / 2; ++it) {
        float4 xv[2][4];
        #pragma unroll
        for (int j = 0; j < 2; ++j)
            #pragma unroll
            for (int k = 0; k < 4; ++k)
                xv[j][k] = xw[(size_t)(it * 2 + j) * (D_MODEL / 4) + k * 64 + lane];

        float sc[2];
        #pragma unroll
        for (int j = 0; j < 2; ++j) {
            float d = xv[j][0].x * q4[0].x;
            d = fmaf(xv[j][0].y, q4[0].y, d);
            d = fmaf(xv[j][0].z, q4[0].z, d);
            d = fmaf(xv[j][0].w, q4[0].w, d);
            #pragma unroll
            for (int k = 1; k < 4; ++k) {
                d = fmaf(xv[j][k].x, q4[k].x, d);
                d = fmaf(xv[j][k].y, q4[k].y, d);
                d = fmaf(xv[j][k].z, q4[k].z, d);
                d = fmaf(xv[j][k].w, q4[k].w, d);
            }
            #pragma unroll
            for (int off = 32; off > 0; off >>= 1)
                d += __shfl_xor(d, off, 64);
            const int s = row0 + it * 2 + j;
            const int mv = u8fmt ? (int)m8[(size_t)b * SEQ + s] : m32[(size_t)b * SEQ + s];
            sc[j] = mv ? NEG_BIG : d * 0.03125f;           // 1/sqrt(1024)
        }

        const float m_new = fmaxf(m_run, fmaxf(sc[0], sc[1]));
        const float resc  = __expf(m_run - m_new);
        l_run *= resc;
        const float w0 = __expf(sc[0] - m_new);
        const float w1 = __expf(sc[1] - m_new);
        l_run += w0 + w1;
        #pragma unroll
        for (int k = 0; k < 4; ++k) {
            acc[k].x = fmaf(w0, xv[0][k].x, fmaf(resc, 0.f, acc[k].x * resc));
            acc[k].x = fmaf(w1, xv[1][k].x, acc[k].x);
            acc[k].y = fmaf(w1, xv[1][k].y, fmaf(w0, xv[0][k].y, acc[k].y * resc));
            acc[k].z = fmaf(w1, xv[1][k].z, fmaf(w0, xv[0][k].z, acc[k].z * resc));
            acc[k].w = fmaf(w1, xv[1][k].w, fmaf(w0, xv[0][k].w, acc[k].w * resc));
        }
        m_run = m_new;
    }

    // ---- merge 4 wave-states into one chunk partial via LDS ----
    if (lane == 0) { sm_m[wv] = m_run; sm_l[wv] = l_run; }
    #pragma unroll
    for (int k = 0; k < 4; ++k)
        reinterpret_cast<float4*>(sm_acc[wv])[k * 64 + lane] = acc[k];
    __syncthreads();

    const float M = fmaxf(fmaxf(sm_m[0], sm_m[1]), fmaxf(sm_m[2], sm_m[3]));
    float f[4];
    #pragma unroll
    for (int w = 0; w < 4; ++w) f[w] = __expf(sm_m[w] - M);

    // wave wv writes column-group wv of the merged accumulator
    float4 o = make_float4(0.f, 0.f, 0.f, 0.f);
    #pragma unroll
    for (int w = 0; w < 4; ++w) {
        float4 a = reinterpret_cast<const float4*>(sm_acc[w])[wv * 64 + lane];
        o.x = fmaf(f[w], a.x, o.x);
        o.y = fmaf(f[w], a.y, o.y);
        o.z = fmaf(f[w], a.z, o.z);
        o.w = fmaf(f[w], a.w, o.w);
    }
    float* accOut = W + 2 * NB * CHUNKS_PER_B + (size_t)bid * D_MODEL;
    reinterpret_cast<float4*>(accOut)[wv * 64 + lane] = o;
    if (tid == 0) {
        W[bid] = M;
        W[NB * CHUNKS_PER_B + bid] = f[0] * sm_l[0] + f[1] * sm_l[1]
                                   + f[2] * sm_l[2] + f[3] * sm_l[3];
    }
}

__global__ __launch_bounds__(64)
void attn_combine(const float* __restrict__ W, float* __restrict__ out)
{
    const int b     = blockIdx.x >> 2;     // 8 batches x 4 D-slices
    const int slice = blockIdx.x & 3;
    const int lane  = threadIdx.x;         // 0..63

    const float*  mArr = W + b * CHUNKS_PER_B;
    const float*  lArr = W + NB * CHUNKS_PER_B + b * CHUNKS_PER_B;
    const float4* accB = reinterpret_cast<const float4*>(
                             W + 2 * NB * CHUNKS_PER_B + (size_t)b * CHUNKS_PER_B * D_MODEL);

    __shared__ float s_f[CHUNKS_PER_B];

    const float m0 = mArr[lane], m1 = mArr[lane + 64];
    float M = fmaxf(m0, m1);
    #pragma unroll
    for (int off = 32; off > 0; off >>= 1) M = fmaxf(M, __shfl_xor(M, off, 64));

    const float f0 = __expf(m0 - M), f1 = __expf(m1 - M);
    s_f[lane] = f0; s_f[lane + 64] = f1;
    float L = fmaf(f0, lArr[lane], f1 * lArr[lane + 64]);
    #pragma unroll
    for (int off = 32; off > 0; off >>= 1) L += __shfl_xor(L, off, 64);
    __syncthreads();

    float4 o = make_float4(0.f, 0.f, 0.f, 0.f);
    #pragma unroll 8
    for (int k = 0; k < CHUNKS_PER_B; ++k) {
        const float  f = s_f[k];
        const float4 a = accB[(size_t)k * (D_MODEL / 4) + slice * 64 + lane];
        o.x = fmaf(f, a.x, o.x);
        o.y = fmaf(f, a.y, o.y);
        o.z = fmaf(f, a.z, o.z);
        o.w = fmaf(f, a.w, o.w);
    }
    const float inv = 1.f / L;
    reinterpret_cast<float4*>(out)[b * (D_MODEL / 4) + slice * 64 + lane] =
        make_float4(o.x * inv, o.y * inv, o.z * inv, o.w * inv);
}

extern "C" void kernel_launch(void* const* d_in, const int* in_sizes, int n_in,
                              void* d_out, int out_size, void* d_ws, size_t ws_size,
                              hipStream_t stream) {
    const float* x    = (const float*)d_in[0];
    const void*  mask = d_in[1];
    const float* q    = (const float*)d_in[2];
    float* out = (float*)d_out;
    float* W   = (float*)d_ws;

    attn_partial<<<NB * CHUNKS_PER_B, THREADS, 0, stream>>>(x, mask, q, W);
    attn_combine<<<NB * 4, 64, 0, stream>>>(W, out);
}